// Round 1
// baseline (2757.086 us; speedup 1.0000x reference)
//
#include <hip/hip_runtime.h>

// Problem constants
#define IRR    56          // irreps dim per node
#define EF     48          // edge feature dim
#define WN     832         // W_NUMEL
#define NEDGE  160000
#define NNODE  8000
#define K1     49          // 48 + bias row
#define KP     52          // K padded to multiple of 4
#define TE     32          // edges per block
#define NT     256         // threads per block
#define CHUNK  128         // W2 columns per chunk
#define NCHUNK 7           // ceil(832/128)

#define INV_SQRT3 0.5773502691896258f
#define INV_SQRT2 0.7071067811865476f
#define A_SCAL    0.22360679774997896f   // 1/sqrt(16+4)
#define A_VEC     0.20412414523193154f   // 1/sqrt(16+8)

// Union LDS region layout (pre-chunk-loop phase); region size KP*CHUNK = 6656 floats
#define U_GATHER 0          // TE*IRR  = 1792 floats: gathered node_attr rows
#define U_EDGE   1792       // TE*K1   = 1568 floats: edge_attr tile (+bias 1.0 col), row stride 49
#define U_W1     3360       // K1*EF   = 2352 floats: fc_w1 + fc_b1 row -> ends at 5712

__global__ __launch_bounds__(NT) void tp_fused(
    const float* __restrict__ node_attr,
    const float* __restrict__ edge_attr,
    const float* __restrict__ edge_sh,
    const float* __restrict__ fc_w1,
    const float* __restrict__ fc_b1,
    const float* __restrict__ fc_w2,
    const float* __restrict__ fc_b2,
    const int*   __restrict__ edge_index,
    float* __restrict__ accum,
    float* __restrict__ counts)
{
    __shared__ __align__(16) float U[KP * CHUNK];   // 26624 B
    __shared__ __align__(16) float sH[TE][KP];      // h tile (+1.0 bias col, zero pad) 6656 B
    __shared__ float sO[TE][IRR];                   // per-edge output accum 7168 B
    __shared__ float sF[TE][120];                   // precomputed TP input features 15360 B
    __shared__ float sS1[TE][3];
    __shared__ int   sSrc[TE];
    __shared__ int   sDst[TE];

    const int tid = threadIdx.x;
    const int e0  = blockIdx.x * TE;

    if (tid < TE) {
        sSrc[tid] = edge_index[e0 + tid];           // edge_index[0] = src
        sDst[tid] = edge_index[NEDGE + e0 + tid];   // edge_index[1] = dst
    }
    for (int idx = tid; idx < TE * IRR; idx += NT) ((float*)sO)[idx] = 0.f;
    __syncthreads();

    // ---- stage: gather node rows, edge_attr tile, W1+b1 (all in union region U) ----
    for (int idx = tid; idx < TE * IRR; idx += NT) {
        int e = idx / IRR, c = idx - e * IRR;
        U[U_GATHER + idx] = node_attr[(size_t)sDst[e] * IRR + c];
    }
    for (int idx = tid; idx < TE * EF; idx += NT) {
        int e = idx / EF, k = idx - e * EF;
        U[U_EDGE + e * K1 + k] = edge_attr[(size_t)(e0 + e) * EF + k];
    }
    if (tid < TE) U[U_EDGE + tid * K1 + EF] = 1.0f;   // bias column
    for (int idx = tid; idx < K1 * EF; idx += NT) {
        int k = idx / EF, c = idx - k * EF;
        U[U_W1 + idx] = (k < EF) ? fc_w1[k * EF + c] : fc_b1[c];
    }
    __syncthreads();

    // ---- per-edge TP input features F (scales folded in) ----
    if (tid < TE) {
        const float* x = &U[U_GATHER + tid * IRR];
        const float s0 = edge_sh[(size_t)(e0 + tid) * 4 + 0];
        const float sx = edge_sh[(size_t)(e0 + tid) * 4 + 1];
        const float sy = edge_sh[(size_t)(e0 + tid) * 4 + 2];
        const float sz = edge_sh[(size_t)(e0 + tid) * 4 + 3];
        float* F = sF[tid];
        const float c0S = s0 * A_SCAL;
        const float c0V = s0 * A_VEC;
        const float cD3 = INV_SQRT3 * A_SCAL;
        const float cC2 = INV_SQRT2 * A_VEC;
        #pragma unroll
        for (int u = 0; u < 16; u++) {
            F[0 + u]   = x[u] * c0S;           // fA0: x0e*s0*A_SCAL
            F[20 + u]  = x[u] * A_VEC;         // fA1: x0e*A_VEC (s1 at consume)
            F[84 + u]  = x[40 + u] * A_VEC;    // fD1e: x0o*A_VEC (s1 at consume)
            F[104 + u] = x[40 + u] * c0S;      // fD0o: x0o*s0*A_SCAL
        }
        #pragma unroll
        for (int u = 0; u < 4; u++) {
            float a0 = x[16 + u*3 + 0], a1 = x[16 + u*3 + 1], a2 = x[16 + u*3 + 2]; // x1o[u]
            float b0 = x[28 + u*3 + 0], b1 = x[28 + u*3 + 1], b2 = x[28 + u*3 + 2]; // x1e[u]
            F[16 + u]  = (a0*sx + a1*sy + a2*sz) * cD3;   // fB0: dot_b*A_SCAL
            F[100 + u] = (b0*sx + b1*sy + b2*sz) * cD3;   // fC0o: dot_c*A_SCAL
            // fC1: cross(x1e,s1)*INV_SQRT2*A_VEC
            F[48 + u*3 + 0] = (b1*sz - b2*sy) * cC2;
            F[48 + u*3 + 1] = (b2*sx - b0*sz) * cC2;
            F[48 + u*3 + 2] = (b0*sy - b1*sx) * cC2;
            // fB1e: cross(x1o,s1)*INV_SQRT2*A_VEC
            F[60 + u*3 + 0] = (a1*sz - a2*sy) * cC2;
            F[60 + u*3 + 1] = (a2*sx - a0*sz) * cC2;
            F[60 + u*3 + 2] = (a0*sy - a1*sx) * cC2;
            // fB1: x1o*s0*A_VEC ; fC1e: x1e*s0*A_VEC
            F[36 + u*3 + 0] = a0 * c0V; F[36 + u*3 + 1] = a1 * c0V; F[36 + u*3 + 2] = a2 * c0V;
            F[72 + u*3 + 0] = b0 * c0V; F[72 + u*3 + 1] = b1 * c0V; F[72 + u*3 + 2] = b2 * c0V;
        }
        sS1[tid][0] = sx; sS1[tid][1] = sy; sS1[tid][2] = sz;
    }

    // ---- GEMM1: h = relu(edge_attr @ W1 + b1) -> sH (192 threads) ----
    if (tid < 192) {
        const int g = tid / EF;        // 0..3 (edge group of 8)
        const int c = tid - g * EF;    // 0..47
        float acc[8];
        #pragma unroll
        for (int j = 0; j < 8; j++) acc[j] = 0.f;
        for (int k = 0; k < K1; k++) {
            float b = U[U_W1 + k * EF + c];
            #pragma unroll
            for (int j = 0; j < 8; j++) acc[j] += U[U_EDGE + (g*8 + j) * K1 + k] * b;
        }
        #pragma unroll
        for (int j = 0; j < 8; j++) sH[g*8 + j][c] = fmaxf(acc[j], 0.f);
    }
    if (tid < TE) { sH[tid][48] = 1.0f; sH[tid][49] = 0.f; sH[tid][50] = 0.f; sH[tid][51] = 0.f; }
    __syncthreads();

    // ---- chunk loop: P = sH @ W2chunk, consumed immediately into sO ----
    const int ty = tid >> 5;   // 0..7  -> 4 edges each
    const int tx = tid & 31;   // 0..31 -> 4 cols each
    for (int ch = 0; ch < NCHUNK; ch++) {
        const int col0 = ch * CHUNK;
        for (int idx = tid; idx < KP * CHUNK; idx += NT) {
            int k = idx / CHUNK, c = idx - k * CHUNK;
            int gc = col0 + c;
            float v = 0.f;
            if (gc < WN) {
                if (k < EF)       v = fc_w2[(size_t)k * WN + gc];
                else if (k == EF) v = fc_b2[gc];
            }
            U[idx] = v;
        }
        __syncthreads();

        float acc[4][4];
        #pragma unroll
        for (int j = 0; j < 4; j++) { acc[j][0]=0.f; acc[j][1]=0.f; acc[j][2]=0.f; acc[j][3]=0.f; }
        for (int k = 0; k < KP; k += 4) {
            float4 w0 = *(const float4*)&U[(k+0) * CHUNK + tx*4];
            float4 w1 = *(const float4*)&U[(k+1) * CHUNK + tx*4];
            float4 w2 = *(const float4*)&U[(k+2) * CHUNK + tx*4];
            float4 w3 = *(const float4*)&U[(k+3) * CHUNK + tx*4];
            #pragma unroll
            for (int j = 0; j < 4; j++) {
                float4 a = *(const float4*)&sH[ty*4 + j][k];
                acc[j][0] += a.x*w0.x + a.y*w1.x + a.z*w2.x + a.w*w3.x;
                acc[j][1] += a.x*w0.y + a.y*w1.y + a.z*w2.y + a.w*w3.y;
                acc[j][2] += a.x*w0.z + a.y*w1.z + a.z*w2.z + a.w*w3.z;
                acc[j][3] += a.x*w0.w + a.y*w1.w + a.z*w2.w + a.w*w3.w;
            }
        }

        #pragma unroll
        for (int j = 0; j < 4; j++) {
            const int e = ty*4 + j;
            const float* F = sF[e];
            #pragma unroll
            for (int m = 0; m < 4; m++) {
                const int c = col0 + tx*4 + m;
                if (c >= WN) continue;
                const float P = acc[j][m];
                if (c < 256) {                       // wA0 (16x16) -> o0e
                    atomicAdd(&sO[e][c & 15], F[c >> 4] * P);
                } else if (c < 320) {                // wB0 (4x16) -> o0e
                    int q = c - 256;
                    atomicAdd(&sO[e][q & 15], F[16 + (q >> 4)] * P);
                } else if (c < 384) {                // wA1 (16x4) -> o1o, *s1
                    int q = c - 320; int v = q & 3;
                    float t = F[20 + (q >> 2)] * P;
                    atomicAdd(&sO[e][16 + v*3 + 0], t * sS1[e][0]);
                    atomicAdd(&sO[e][16 + v*3 + 1], t * sS1[e][1]);
                    atomicAdd(&sO[e][16 + v*3 + 2], t * sS1[e][2]);
                } else if (c < 400) {                // wB1 (4x4) -> o1o
                    int q = c - 384; int u = q >> 2, v = q & 3;
                    atomicAdd(&sO[e][16 + v*3 + 0], F[36 + u*3 + 0] * P);
                    atomicAdd(&sO[e][16 + v*3 + 1], F[36 + u*3 + 1] * P);
                    atomicAdd(&sO[e][16 + v*3 + 2], F[36 + u*3 + 2] * P);
                } else if (c < 416) {                // wC1 (4x4) -> o1o
                    int q = c - 400; int u = q >> 2, v = q & 3;
                    atomicAdd(&sO[e][16 + v*3 + 0], F[48 + u*3 + 0] * P);
                    atomicAdd(&sO[e][16 + v*3 + 1], F[48 + u*3 + 1] * P);
                    atomicAdd(&sO[e][16 + v*3 + 2], F[48 + u*3 + 2] * P);
                } else if (c < 432) {                // wB1e (4x4) -> o1e
                    int q = c - 416; int u = q >> 2, v = q & 3;
                    atomicAdd(&sO[e][28 + v*3 + 0], F[60 + u*3 + 0] * P);
                    atomicAdd(&sO[e][28 + v*3 + 1], F[60 + u*3 + 1] * P);
                    atomicAdd(&sO[e][28 + v*3 + 2], F[60 + u*3 + 2] * P);
                } else if (c < 448) {                // wC1e (4x4) -> o1e
                    int q = c - 432; int u = q >> 2, v = q & 3;
                    atomicAdd(&sO[e][28 + v*3 + 0], F[72 + u*3 + 0] * P);
                    atomicAdd(&sO[e][28 + v*3 + 1], F[72 + u*3 + 1] * P);
                    atomicAdd(&sO[e][28 + v*3 + 2], F[72 + u*3 + 2] * P);
                } else if (c < 512) {                // wD1e (16x4) -> o1e, *s1
                    int q = c - 448; int v = q & 3;
                    float t = F[84 + (q >> 2)] * P;
                    atomicAdd(&sO[e][28 + v*3 + 0], t * sS1[e][0]);
                    atomicAdd(&sO[e][28 + v*3 + 1], t * sS1[e][1]);
                    atomicAdd(&sO[e][28 + v*3 + 2], t * sS1[e][2]);
                } else if (c < 576) {                // wC0o (4x16) -> o0o
                    int q = c - 512;
                    atomicAdd(&sO[e][40 + (q & 15)], F[100 + (q >> 4)] * P);
                } else {                             // wD0o (16x16) -> o0o
                    int q = c - 576;
                    atomicAdd(&sO[e][40 + (q & 15)], F[104 + (q >> 4)] * P);
                }
            }
        }
        __syncthreads();
    }

    // ---- scatter to global accumulators ----
    for (int idx = tid; idx < TE * IRR; idx += NT) {
        int e = idx / IRR, c = idx - e * IRR;
        unsafeAtomicAdd(&accum[(size_t)sSrc[e] * IRR + c], sO[e][c]);
    }
    if (tid < TE) unsafeAtomicAdd(&counts[sSrc[tid]], 1.0f);
}

__global__ void tp_divide(const float* __restrict__ accum,
                          const float* __restrict__ counts,
                          float* __restrict__ out)
{
    int idx = blockIdx.x * blockDim.x + threadIdx.x;
    if (idx < NNODE * IRR) {
        out[idx] = accum[idx] / fmaxf(counts[idx / IRR], 1.0f);
    }
}

extern "C" void kernel_launch(void* const* d_in, const int* in_sizes, int n_in,
                              void* d_out, int out_size, void* d_ws, size_t ws_size,
                              hipStream_t stream) {
    const float* node_attr = (const float*)d_in[0];
    const float* edge_attr = (const float*)d_in[1];
    const float* edge_sh   = (const float*)d_in[2];
    const float* fc_w1     = (const float*)d_in[3];
    const float* fc_b1     = (const float*)d_in[4];
    const float* fc_w2     = (const float*)d_in[5];
    const float* fc_b2     = (const float*)d_in[6];
    const int*   edge_index= (const int*)d_in[7];

    float* accum  = (float*)d_ws;
    float* counts = accum + (size_t)NNODE * IRR;

    hipMemsetAsync(d_ws, 0, ((size_t)NNODE * IRR + NNODE) * sizeof(float), stream);

    tp_fused<<<NEDGE / TE, NT, 0, stream>>>(node_attr, edge_attr, edge_sh,
                                            fc_w1, fc_b1, fc_w2, fc_b2,
                                            edge_index, accum, counts);

    tp_divide<<<(NNODE * IRR + NT - 1) / NT, NT, 0, stream>>>(accum, counts, (float*)d_out);
}

// Round 2
// 595.772 us; speedup vs baseline: 4.6278x; 4.6278x over previous
//
#include <hip/hip_runtime.h>

#define IRR    56
#define EF     48
#define WN     832
#define NEDGE  160000
#define NNODE  8000
#define TE     32
#define NT     256
#define NBLK   (NEDGE / TE)

#define SP_STRIDE 424    // ushorts; 848B rows: 16B-aligned, uniform bank spread
#define SH_STRIDE 72     // ushorts; 144B rows: 16B-aligned
#define SF_STRIDE 121    // floats; odd dword stride -> conflict-free e-indexed reads

#define INV_SQRT3 0.5773502691896258f
#define INV_SQRT2 0.7071067811865476f
#define A_SCAL    0.22360679774997896f   // 1/sqrt(20)
#define A_VEC     0.20412414523193154f   // 1/sqrt(24)

typedef __bf16 bf16x8 __attribute__((ext_vector_type(8)));
typedef float  f32x4  __attribute__((ext_vector_type(4)));
typedef unsigned short u16x8 __attribute__((ext_vector_type(8)));
typedef unsigned short u16x4 __attribute__((ext_vector_type(4)));

__device__ __forceinline__ unsigned short f2bf(float f) {
    unsigned int u = __builtin_bit_cast(unsigned int, f);
    u += 0x7FFFu + ((u >> 16) & 1u);          // RNE
    return (unsigned short)(u >> 16);
}
__device__ __forceinline__ float bf2f(unsigned short h) {
    unsigned int u = ((unsigned int)h) << 16;
    return __builtin_bit_cast(float, u);
}

// Build bf16 transposed weight tables [N][64]: k<48 = W[k][n], k==48 = bias[n], k>48 = 0.
__global__ void preconvert(const float* __restrict__ w1, const float* __restrict__ b1,
                           const float* __restrict__ w2, const float* __restrict__ b2,
                           unsigned short* __restrict__ W1T, unsigned short* __restrict__ W2T)
{
    int idx = blockIdx.x * 256 + threadIdx.x;
    if (idx < WN * 64) {
        int n = idx >> 6, k = idx & 63;
        float v = (k < EF) ? w2[k * WN + n] : ((k == EF) ? b2[n] : 0.f);
        W2T[idx] = f2bf(v);
    }
    if (idx < EF * 64) {
        int n = idx >> 6, k = idx & 63;
        float v = (k < EF) ? w1[k * EF + n] : ((k == EF) ? b1[n] : 0.f);
        W1T[idx] = f2bf(v);
    }
}

__global__ __launch_bounds__(NT) void tp_fused(
    const float* __restrict__ node_attr,
    const float* __restrict__ edge_attr,
    const float* __restrict__ edge_sh,
    const int*   __restrict__ edge_index,
    const unsigned short* __restrict__ W1T,
    const unsigned short* __restrict__ W2T,
    float* __restrict__ accum,
    float* __restrict__ counts)
{
    __shared__ __align__(16) unsigned short sP[TE * SP_STRIDE]; // 27136B; overlaid with gather f32[32*56]=7168B
    __shared__ __align__(16) unsigned short sH[TE * SH_STRIDE]; // 4608B  h tile, A-operand layout
    __shared__ float sF[TE * SF_STRIDE];                        // 15488B precomputed TP features
    __shared__ float sS1[TE][4];
    __shared__ int   sSrc[TE], sDst[TE];

    const int tid  = threadIdx.x;
    const int e0   = blockIdx.x * TE;
    const int lane = tid & 63;
    const int wv   = tid >> 6;
    const int m    = lane & 15;   // MFMA row/col lane index
    const int quad = lane >> 4;

    if (tid < TE) {
        sSrc[tid] = edge_index[e0 + tid];
        sDst[tid] = edge_index[NEDGE + e0 + tid];
    }
    __syncthreads();

    // ---- gather node rows into sG (overlay on sP) ----
    float* sG = (float*)sP;
    for (int idx = tid; idx < TE * IRR; idx += NT) {
        int ge = idx / IRR, c = idx - ge * IRR;
        sG[idx] = node_attr[(size_t)sDst[ge] * IRR + c];
    }
    __syncthreads();

    // ===== phase 2: GEMM1 via MFMA (waves 0..2, ntile=wave), F features + sH pad (wave 3) =====
    if (wv < 3) {
        const int nt = wv;
        bf16x8 b0 = __builtin_bit_cast(bf16x8, *(const u16x8*)&W1T[(nt*16 + m)*64 + quad*8]);
        bf16x8 b1 = __builtin_bit_cast(bf16x8, *(const u16x8*)&W1T[(nt*16 + m)*64 + 32 + quad*8]);
        for (int rt = 0; rt < 2; rt++) {
            const float* arow = &edge_attr[(size_t)(e0 + rt*16 + m) * EF];
            float av0[8], av1[8];
            {
                float4 p0 = *(const float4*)(arow + quad*8);
                float4 p1 = *(const float4*)(arow + quad*8 + 4);
                av0[0]=p0.x; av0[1]=p0.y; av0[2]=p0.z; av0[3]=p0.w;
                av0[4]=p1.x; av0[5]=p1.y; av0[6]=p1.z; av0[7]=p1.w;
            }
            if (quad < 2) {
                float4 p0 = *(const float4*)(arow + 32 + quad*8);
                float4 p1 = *(const float4*)(arow + 32 + quad*8 + 4);
                av1[0]=p0.x; av1[1]=p0.y; av1[2]=p0.z; av1[3]=p0.w;
                av1[4]=p1.x; av1[5]=p1.y; av1[6]=p1.z; av1[7]=p1.w;
            } else {
                #pragma unroll
                for (int j = 0; j < 8; j++) av1[j] = 0.f;
                if (quad == 2) av1[0] = 1.f;       // bias k=48
            }
            u16x8 ua0, ua1;
            #pragma unroll
            for (int j = 0; j < 8; j++) { ua0[j] = f2bf(av0[j]); ua1[j] = f2bf(av1[j]); }
            f32x4 acc = {0.f, 0.f, 0.f, 0.f};
            acc = __builtin_amdgcn_mfma_f32_16x16x32_bf16(__builtin_bit_cast(bf16x8, ua0), b0, acc, 0, 0, 0);
            acc = __builtin_amdgcn_mfma_f32_16x16x32_bf16(__builtin_bit_cast(bf16x8, ua1), b1, acc, 0, 0, 0);
            #pragma unroll
            for (int r = 0; r < 4; r++) {
                int row = rt*16 + quad*4 + r;      // C layout: row=quad*4+r, col=lane&15
                sH[row * SH_STRIDE + nt*16 + m] = f2bf(fmaxf(acc[r], 0.f));
            }
        }
    } else {
        if (lane < 32) {
            const int ee = lane;
            const float* x = &sG[ee * IRR];
            float4 sh4 = *(const float4*)&edge_sh[(size_t)(e0 + ee) * 4];
            const float s0 = sh4.x, sx = sh4.y, sy = sh4.z, sz = sh4.w;
            float* F = &sF[ee * SF_STRIDE];
            const float c0S = s0 * A_SCAL;
            const float c0V = s0 * A_VEC;
            const float cD3 = INV_SQRT3 * A_SCAL;
            const float cC2 = INV_SQRT2 * A_VEC;
            #pragma unroll
            for (int u = 0; u < 16; u++) {
                float x0e = x[u], x0o = x[40 + u];
                F[u]       = x0e * c0S;    // wA0
                F[20 + u]  = x0e * A_VEC;  // wA1 (s1 applied at consume)
                F[84 + u]  = x0o * A_VEC;  // wD1e (s1 at consume)
                F[104 + u] = x0o * c0S;    // wD0o
            }
            #pragma unroll
            for (int u = 0; u < 4; u++) {
                float a0 = x[16 + u*3], a1 = x[16 + u*3 + 1], a2 = x[16 + u*3 + 2]; // x1o
                float b0 = x[28 + u*3], b1 = x[28 + u*3 + 1], b2 = x[28 + u*3 + 2]; // x1e
                F[16 + u]  = (a0*sx + a1*sy + a2*sz) * cD3;   // wB0 (dot_b)
                F[100 + u] = (b0*sx + b1*sy + b2*sz) * cD3;   // wC0o (dot_c)
                F[48 + u*3 + 0] = (b1*sz - b2*sy) * cC2;      // wC1: cross(x1e,s1)
                F[48 + u*3 + 1] = (b2*sx - b0*sz) * cC2;
                F[48 + u*3 + 2] = (b0*sy - b1*sx) * cC2;
                F[60 + u*3 + 0] = (a1*sz - a2*sy) * cC2;      // wB1e: cross(x1o,s1)
                F[60 + u*3 + 1] = (a2*sx - a0*sz) * cC2;
                F[60 + u*3 + 2] = (a0*sy - a1*sx) * cC2;
                F[36 + u*3 + 0] = a0 * c0V;  F[36 + u*3 + 1] = a1 * c0V;  F[36 + u*3 + 2] = a2 * c0V; // wB1
                F[72 + u*3 + 0] = b0 * c0V;  F[72 + u*3 + 1] = b1 * c0V;  F[72 + u*3 + 2] = b2 * c0V; // wC1e
            }
            sS1[ee][0] = sx; sS1[ee][1] = sy; sS1[ee][2] = sz;
        } else {
            const int ee = lane - 32;
            sH[ee * SH_STRIDE + 48] = 0x3F80;  // bf16(1.0) bias column
            #pragma unroll
            for (int k = 49; k < 64; k++) sH[ee * SH_STRIDE + k] = 0;
        }
    }
    __syncthreads();

    // ===== GEMM2 A-fragments (held across both halves) =====
    bf16x8 A00 = __builtin_bit_cast(bf16x8, *(const u16x8*)&sH[ m        * SH_STRIDE + quad*8]);
    bf16x8 A01 = __builtin_bit_cast(bf16x8, *(const u16x8*)&sH[ m        * SH_STRIDE + 32 + quad*8]);
    bf16x8 A10 = __builtin_bit_cast(bf16x8, *(const u16x8*)&sH[(16 + m)  * SH_STRIDE + quad*8]);
    bf16x8 A11 = __builtin_bit_cast(bf16x8, *(const u16x8*)&sH[(16 + m)  * SH_STRIDE + 32 + quad*8]);

    const int ce  = lane & 31;          // consume: edge owned by lane
    const int sub = lane >> 5;          // 2-way u-split within wave
    const unsigned short* Pr = sP + ce * SP_STRIDE;
    const float* Fv = &sF[ce * SF_STRIDE];

    for (int half = 0; half < 2; half++) {
        // ---- GEMM2: 26 ntiles split over 4 waves; P -> sP (bf16) ----
        for (int nt = half*26 + wv; nt < half*26 + 26; nt += 4) {
            bf16x8 B0 = __builtin_bit_cast(bf16x8, *(const u16x8*)&W2T[(size_t)(nt*16 + m)*64 + quad*8]);
            bf16x8 B1 = __builtin_bit_cast(bf16x8, *(const u16x8*)&W2T[(size_t)(nt*16 + m)*64 + 32 + quad*8]);
            f32x4 c0 = {0.f,0.f,0.f,0.f}, c1 = {0.f,0.f,0.f,0.f};
            c0 = __builtin_amdgcn_mfma_f32_16x16x32_bf16(A00, B0, c0, 0, 0, 0);
            c0 = __builtin_amdgcn_mfma_f32_16x16x32_bf16(A01, B1, c0, 0, 0, 0);
            c1 = __builtin_amdgcn_mfma_f32_16x16x32_bf16(A10, B0, c1, 0, 0, 0);
            c1 = __builtin_amdgcn_mfma_f32_16x16x32_bf16(A11, B1, c1, 0, 0, 0);
            int colw = (nt - half*26)*16 + m;
            #pragma unroll
            for (int r = 0; r < 4; r++) {
                sP[(quad*4 + r)      * SP_STRIDE + colw] = f2bf(c0[r]);
                sP[(16 + quad*4 + r) * SP_STRIDE + colw] = f2bf(c1[r]);
            }
        }
        __syncthreads();

        // ---- consume (atomic-free; vector LDS reads; shfl-combined) ----
        if (half == 0) {
            if (wv == 0) {
                // O0E: o0e[v] = sum_{j<20} F[j] * P[j*16+v]   (wA0 then wB0, contiguous)
                float acc[16];
                #pragma unroll
                for (int v = 0; v < 16; v++) acc[v] = 0.f;
                #pragma unroll
                for (int jj = 0; jj < 10; jj++) {
                    int j = sub*10 + jj;
                    float f = Fv[j];
                    u16x8 p0 = *(const u16x8*)(Pr + j*16);
                    u16x8 p1 = *(const u16x8*)(Pr + j*16 + 8);
                    #pragma unroll
                    for (int v = 0; v < 8; v++) {
                        acc[v]   += f * bf2f(p0[v]);
                        acc[8+v] += f * bf2f(p1[v]);
                    }
                }
                int base = sSrc[ce] * IRR;
                #pragma unroll
                for (int v = 0; v < 16; v++) {
                    float tot = acc[v] + __shfl_down(acc[v], 32, 64);
                    if (sub == 0) unsafeAtomicAdd(&accum[base + v], tot);
                }
            } else if (wv == 1) {
                // O1O: cols 320 + j*4 + v, j<16 = wA1 (dot path, *s1), j>=16 -> F[36+3u+i] (wB1,wC1 unified)
                float sA[4] = {0.f,0.f,0.f,0.f};
                float acc[3][4];
                #pragma unroll
                for (int i = 0; i < 3; i++)
                    #pragma unroll
                    for (int v = 0; v < 4; v++) acc[i][v] = 0.f;
                #pragma unroll
                for (int jj = 0; jj < 12; jj++) {
                    int j = sub*12 + jj;
                    u16x4 p = *(const u16x4*)(Pr + 320 + j*4);
                    float pv[4];
                    #pragma unroll
                    for (int v = 0; v < 4; v++) pv[v] = bf2f(p[v]);
                    if (j < 16) {
                        float f = Fv[20 + j];
                        #pragma unroll
                        for (int v = 0; v < 4; v++) sA[v] += f * pv[v];
                    } else {
                        int u = j - 16;
                        #pragma unroll
                        for (int i = 0; i < 3; i++) {
                            float f = Fv[36 + u*3 + i];
                            #pragma unroll
                            for (int v = 0; v < 4; v++) acc[i][v] += f * pv[v];
                        }
                    }
                }
                int base = sSrc[ce] * IRR;
                float s1v0 = sS1[ce][0], s1v1 = sS1[ce][1], s1v2 = sS1[ce][2];
                #pragma unroll
                for (int v = 0; v < 4; v++) {
                    float sAt = sA[v] + __shfl_down(sA[v], 32, 64);
                    float t0 = acc[0][v] + __shfl_down(acc[0][v], 32, 64);
                    float t1 = acc[1][v] + __shfl_down(acc[1][v], 32, 64);
                    float t2 = acc[2][v] + __shfl_down(acc[2][v], 32, 64);
                    if (sub == 0) {
                        unsafeAtomicAdd(&accum[base + 16 + v*3 + 0], sAt * s1v0 + t0);
                        unsafeAtomicAdd(&accum[base + 16 + v*3 + 1], sAt * s1v1 + t1);
                        unsafeAtomicAdd(&accum[base + 16 + v*3 + 2], sAt * s1v2 + t2);
                    }
                }
            }
        } else {
            if (wv == 2) {
                // O1E: cols j*4 + v (wB1e,wC1e unified F[60+3j+i] for j<8; wD1e dot path j>=8, *s1)
                float sD[4] = {0.f,0.f,0.f,0.f};
                float acc[3][4];
                #pragma unroll
                for (int i = 0; i < 3; i++)
                    #pragma unroll
                    for (int v = 0; v < 4; v++) acc[i][v] = 0.f;
                #pragma unroll
                for (int jj = 0; jj < 12; jj++) {
                    int j = sub*12 + jj;
                    u16x4 p = *(const u16x4*)(Pr + j*4);
                    float pv[4];
                    #pragma unroll
                    for (int v = 0; v < 4; v++) pv[v] = bf2f(p[v]);
                    if (j < 8) {
                        #pragma unroll
                        for (int i = 0; i < 3; i++) {
                            float f = Fv[60 + j*3 + i];
                            #pragma unroll
                            for (int v = 0; v < 4; v++) acc[i][v] += f * pv[v];
                        }
                    } else {
                        float f = Fv[84 + (j - 8)];
                        #pragma unroll
                        for (int v = 0; v < 4; v++) sD[v] += f * pv[v];
                    }
                }
                int base = sSrc[ce] * IRR;
                float s1v0 = sS1[ce][0], s1v1 = sS1[ce][1], s1v2 = sS1[ce][2];
                #pragma unroll
                for (int v = 0; v < 4; v++) {
                    float sDt = sD[v] + __shfl_down(sD[v], 32, 64);
                    float t0 = acc[0][v] + __shfl_down(acc[0][v], 32, 64);
                    float t1 = acc[1][v] + __shfl_down(acc[1][v], 32, 64);
                    float t2 = acc[2][v] + __shfl_down(acc[2][v], 32, 64);
                    if (sub == 0) {
                        unsafeAtomicAdd(&accum[base + 28 + v*3 + 0], sDt * s1v0 + t0);
                        unsafeAtomicAdd(&accum[base + 28 + v*3 + 1], sDt * s1v1 + t1);
                        unsafeAtomicAdd(&accum[base + 28 + v*3 + 2], sDt * s1v2 + t2);
                    }
                }
            } else if (wv == 3) {
                // O0O: o0o[v] = sum_{j<20} F[100+j] * P[(512-416) + j*16 + v]  (wC0o then wD0o, contiguous)
                float acc[16];
                #pragma unroll
                for (int v = 0; v < 16; v++) acc[v] = 0.f;
                #pragma unroll
                for (int jj = 0; jj < 10; jj++) {
                    int j = sub*10 + jj;
                    float f = Fv[100 + j];
                    u16x8 p0 = *(const u16x8*)(Pr + 96 + j*16);
                    u16x8 p1 = *(const u16x8*)(Pr + 96 + j*16 + 8);
                    #pragma unroll
                    for (int v = 0; v < 8; v++) {
                        acc[v]   += f * bf2f(p0[v]);
                        acc[8+v] += f * bf2f(p1[v]);
                    }
                }
                int base = sSrc[ce] * IRR;
                #pragma unroll
                for (int v = 0; v < 16; v++) {
                    float tot = acc[v] + __shfl_down(acc[v], 32, 64);
                    if (sub == 0) unsafeAtomicAdd(&accum[base + 40 + v], tot);
                }
            }
        }
        __syncthreads();
    }

    if (tid < TE) unsafeAtomicAdd(&counts[sSrc[tid]], 1.0f);
}

__global__ void tp_divide(const float* __restrict__ accum,
                          const float* __restrict__ counts,
                          float* __restrict__ out)
{
    int idx = blockIdx.x * blockDim.x + threadIdx.x;
    if (idx < NNODE * IRR) {
        out[idx] = accum[idx] / fmaxf(counts[idx / IRR], 1.0f);
    }
}

extern "C" void kernel_launch(void* const* d_in, const int* in_sizes, int n_in,
                              void* d_out, int out_size, void* d_ws, size_t ws_size,
                              hipStream_t stream) {
    const float* node_attr  = (const float*)d_in[0];
    const float* edge_attr  = (const float*)d_in[1];
    const float* edge_sh    = (const float*)d_in[2];
    const float* fc_w1      = (const float*)d_in[3];
    const float* fc_b1      = (const float*)d_in[4];
    const float* fc_w2      = (const float*)d_in[5];
    const float* fc_b2      = (const float*)d_in[6];
    const int*   edge_index = (const int*)d_in[7];

    float* accum  = (float*)d_ws;
    float* counts = accum + (size_t)NNODE * IRR;
    unsigned short* W2T = (unsigned short*)(counts + NNODE);   // 16B-aligned offset
    unsigned short* W1T = W2T + (size_t)WN * 64;

    hipMemsetAsync(d_ws, 0, ((size_t)NNODE * IRR + NNODE) * sizeof(float), stream);

    preconvert<<<(WN * 64 + 255) / 256, 256, 0, stream>>>(fc_w1, fc_b1, fc_w2, fc_b2, W1T, W2T);

    tp_fused<<<NBLK, NT, 0, stream>>>(node_attr, edge_attr, edge_sh, edge_index,
                                      W1T, W2T, accum, counts);

    tp_divide<<<(NNODE * IRR + NT - 1) / NT, NT, 0, stream>>>(accum, counts, (float*)d_out);
}

// Round 3
// 249.624 us; speedup vs baseline: 11.0450x; 2.3867x over previous
//
#include <hip/hip_runtime.h>

#define IRR    56
#define EF     48
#define WN     832
#define NEDGE  160000
#define NNODE  8000
#define TE     32
#define NT     256
#define NBLK   (NEDGE / TE)

#define SP_STRIDE 424    // ushorts; 848B rows
#define SH_STRIDE 72     // ushorts; 144B rows
#define SO_STRIDE 57     // floats; odd stride -> conflict-free e-indexed access
#define SF_STRIDE 121    // floats

#define INV_SQRT3 0.5773502691896258f
#define INV_SQRT2 0.7071067811865476f
#define A_SCAL    0.22360679774997896f   // 1/sqrt(20)
#define A_VEC     0.20412414523193154f   // 1/sqrt(24)

typedef __bf16 bf16x8 __attribute__((ext_vector_type(8)));
typedef float  f32x4  __attribute__((ext_vector_type(4)));
typedef unsigned short u16x8 __attribute__((ext_vector_type(8)));
typedef unsigned short u16x4 __attribute__((ext_vector_type(4)));

__device__ __forceinline__ unsigned short f2bf(float f) {
    unsigned int u = __builtin_bit_cast(unsigned int, f);
    u += 0x7FFFu + ((u >> 16) & 1u);          // RNE
    return (unsigned short)(u >> 16);
}
__device__ __forceinline__ float bf2f(unsigned short h) {
    unsigned int u = ((unsigned int)h) << 16;
    return __builtin_bit_cast(float, u);
}

// Build bf16 transposed weight tables [N][64]: k<48 = W[k][n], k==48 = bias[n], k>48 = 0.
__global__ void preconvert(const float* __restrict__ w1, const float* __restrict__ b1,
                           const float* __restrict__ w2, const float* __restrict__ b2,
                           unsigned short* __restrict__ W1T, unsigned short* __restrict__ W2T)
{
    int idx = blockIdx.x * 256 + threadIdx.x;
    if (idx < WN * 64) {
        int n = idx >> 6, k = idx & 63;
        float v = (k < EF) ? w2[k * WN + n] : ((k == EF) ? b2[n] : 0.f);
        W2T[idx] = f2bf(v);
    }
    if (idx < EF * 64) {
        int n = idx >> 6, k = idx & 63;
        float v = (k < EF) ? w1[k * EF + n] : ((k == EF) ? b1[n] : 0.f);
        W1T[idx] = f2bf(v);
    }
}

__global__ __launch_bounds__(NT) void tp_fused(
    const float* __restrict__ node_attr,
    const float* __restrict__ edge_attr,
    const float* __restrict__ edge_sh,
    const int*   __restrict__ edge_index,
    const unsigned short* __restrict__ W1T,
    const unsigned short* __restrict__ W2T,
    float* __restrict__ accum,
    float* __restrict__ counts)
{
    __shared__ __align__(16) unsigned short sP[TE * SP_STRIDE];  // 27136B; overlays gather f32 tile
    __shared__ __align__(16) unsigned char  uSHO[TE * SO_STRIDE * 4]; // 7296B: sH (4608B) then sO overlay
    __shared__ float sF[TE * SF_STRIDE];                         // 15488B
    __shared__ float sS1[TE][4];
    __shared__ int   sSrc[TE], sDst[TE];

    unsigned short* sH = (unsigned short*)uSHO;  // live: GEMM1 -> A-frag load
    float*          sO = (float*)uSHO;           // live: consume -> scatter

    const int tid  = threadIdx.x;
    const int e0   = blockIdx.x * TE;
    const int lane = tid & 63;
    const int wv   = tid >> 6;
    const int m    = lane & 15;
    const int quad = lane >> 4;

    if (tid < TE) {
        sSrc[tid] = edge_index[e0 + tid];
        sDst[tid] = edge_index[NEDGE + e0 + tid];
    }
    __syncthreads();

    // ---- gather node rows into sG (overlay on sP) ----
    float* sG = (float*)sP;
    for (int idx = tid; idx < TE * IRR; idx += NT) {
        int ge = idx / IRR, c = idx - ge * IRR;
        sG[idx] = node_attr[(size_t)sDst[ge] * IRR + c];
    }
    __syncthreads();

    // ===== GEMM1 via MFMA (waves 0..2), F features + sH bias pad (wave 3) =====
    if (wv < 3) {
        const int nt = wv;
        bf16x8 b0 = __builtin_bit_cast(bf16x8, *(const u16x8*)&W1T[(nt*16 + m)*64 + quad*8]);
        bf16x8 b1 = __builtin_bit_cast(bf16x8, *(const u16x8*)&W1T[(nt*16 + m)*64 + 32 + quad*8]);
        for (int rt = 0; rt < 2; rt++) {
            const float* arow = &edge_attr[(size_t)(e0 + rt*16 + m) * EF];
            float av0[8], av1[8];
            {
                float4 p0 = *(const float4*)(arow + quad*8);
                float4 p1 = *(const float4*)(arow + quad*8 + 4);
                av0[0]=p0.x; av0[1]=p0.y; av0[2]=p0.z; av0[3]=p0.w;
                av0[4]=p1.x; av0[5]=p1.y; av0[6]=p1.z; av0[7]=p1.w;
            }
            if (quad < 2) {
                float4 p0 = *(const float4*)(arow + 32 + quad*8);
                float4 p1 = *(const float4*)(arow + 32 + quad*8 + 4);
                av1[0]=p0.x; av1[1]=p0.y; av1[2]=p0.z; av1[3]=p0.w;
                av1[4]=p1.x; av1[5]=p1.y; av1[6]=p1.z; av1[7]=p1.w;
            } else {
                #pragma unroll
                for (int j = 0; j < 8; j++) av1[j] = 0.f;
                if (quad == 2) av1[0] = 1.f;       // bias k=48
            }
            u16x8 ua0, ua1;
            #pragma unroll
            for (int j = 0; j < 8; j++) { ua0[j] = f2bf(av0[j]); ua1[j] = f2bf(av1[j]); }
            f32x4 acc = {0.f, 0.f, 0.f, 0.f};
            acc = __builtin_amdgcn_mfma_f32_16x16x32_bf16(__builtin_bit_cast(bf16x8, ua0), b0, acc, 0, 0, 0);
            acc = __builtin_amdgcn_mfma_f32_16x16x32_bf16(__builtin_bit_cast(bf16x8, ua1), b1, acc, 0, 0, 0);
            #pragma unroll
            for (int r = 0; r < 4; r++) {
                int row = rt*16 + quad*4 + r;
                sH[row * SH_STRIDE + nt*16 + m] = f2bf(fmaxf(acc[r], 0.f));
            }
        }
    } else {
        if (lane < 32) {
            const int ee = lane;
            const float* x = &sG[ee * IRR];
            float4 sh4 = *(const float4*)&edge_sh[(size_t)(e0 + ee) * 4];
            const float s0 = sh4.x, sx = sh4.y, sy = sh4.z, sz = sh4.w;
            float* F = &sF[ee * SF_STRIDE];
            const float c0S = s0 * A_SCAL;
            const float c0V = s0 * A_VEC;
            const float cD3 = INV_SQRT3 * A_SCAL;
            const float cC2 = INV_SQRT2 * A_VEC;
            #pragma unroll
            for (int u = 0; u < 16; u++) {
                float x0e = x[u], x0o = x[40 + u];
                F[u]       = x0e * c0S;
                F[20 + u]  = x0e * A_VEC;
                F[84 + u]  = x0o * A_VEC;
                F[104 + u] = x0o * c0S;
            }
            #pragma unroll
            for (int u = 0; u < 4; u++) {
                float a0 = x[16 + u*3], a1 = x[16 + u*3 + 1], a2 = x[16 + u*3 + 2]; // x1o
                float b0 = x[28 + u*3], b1 = x[28 + u*3 + 1], b2 = x[28 + u*3 + 2]; // x1e
                F[16 + u]  = (a0*sx + a1*sy + a2*sz) * cD3;   // dot_b
                F[100 + u] = (b0*sx + b1*sy + b2*sz) * cD3;   // dot_c
                F[48 + u*3 + 0] = (b1*sz - b2*sy) * cC2;      // cross(x1e,s1)
                F[48 + u*3 + 1] = (b2*sx - b0*sz) * cC2;
                F[48 + u*3 + 2] = (b0*sy - b1*sx) * cC2;
                F[60 + u*3 + 0] = (a1*sz - a2*sy) * cC2;      // cross(x1o,s1)
                F[60 + u*3 + 1] = (a2*sx - a0*sz) * cC2;
                F[60 + u*3 + 2] = (a0*sy - a1*sx) * cC2;
                F[36 + u*3 + 0] = a0 * c0V;  F[36 + u*3 + 1] = a1 * c0V;  F[36 + u*3 + 2] = a2 * c0V;
                F[72 + u*3 + 0] = b0 * c0V;  F[72 + u*3 + 1] = b1 * c0V;  F[72 + u*3 + 2] = b2 * c0V;
            }
            sS1[ee][0] = sx; sS1[ee][1] = sy; sS1[ee][2] = sz;
        } else {
            const int ee = lane - 32;
            sH[ee * SH_STRIDE + 48] = 0x3F80;  // bf16(1.0) bias column
            #pragma unroll
            for (int k = 49; k < 64; k++) sH[ee * SH_STRIDE + k] = 0;
        }
    }
    __syncthreads();

    // ===== GEMM2 A-fragments (sH dead afterwards; sO overlays it) =====
    bf16x8 A00 = __builtin_bit_cast(bf16x8, *(const u16x8*)&sH[ m        * SH_STRIDE + quad*8]);
    bf16x8 A01 = __builtin_bit_cast(bf16x8, *(const u16x8*)&sH[ m        * SH_STRIDE + 32 + quad*8]);
    bf16x8 A10 = __builtin_bit_cast(bf16x8, *(const u16x8*)&sH[(16 + m)  * SH_STRIDE + quad*8]);
    bf16x8 A11 = __builtin_bit_cast(bf16x8, *(const u16x8*)&sH[(16 + m)  * SH_STRIDE + 32 + quad*8]);

    const int ce  = lane & 31;
    const int sub = lane >> 5;
    const unsigned short* Pr = sP + ce * SP_STRIDE;
    const float* Fv = &sF[ce * SF_STRIDE];

    for (int half = 0; half < 2; half++) {
        // ---- GEMM2 with depth-1 B prefetch; P -> sP (bf16) ----
        {
            const int ntEnd = half*26 + 26;
            int nt = half*26 + wv;
            u16x8 rB0, rB1, nB0, nB1;
            if (nt < ntEnd) {
                rB0 = *(const u16x8*)&W2T[(size_t)(nt*16 + m)*64 + quad*8];
                rB1 = *(const u16x8*)&W2T[(size_t)(nt*16 + m)*64 + 32 + quad*8];
            }
            while (nt < ntEnd) {
                int ntn = nt + 4;
                if (ntn < ntEnd) {
                    nB0 = *(const u16x8*)&W2T[(size_t)(ntn*16 + m)*64 + quad*8];
                    nB1 = *(const u16x8*)&W2T[(size_t)(ntn*16 + m)*64 + 32 + quad*8];
                }
                f32x4 c0 = {0.f,0.f,0.f,0.f}, c1 = {0.f,0.f,0.f,0.f};
                c0 = __builtin_amdgcn_mfma_f32_16x16x32_bf16(A00, __builtin_bit_cast(bf16x8, rB0), c0, 0, 0, 0);
                c0 = __builtin_amdgcn_mfma_f32_16x16x32_bf16(A01, __builtin_bit_cast(bf16x8, rB1), c0, 0, 0, 0);
                c1 = __builtin_amdgcn_mfma_f32_16x16x32_bf16(A10, __builtin_bit_cast(bf16x8, rB0), c1, 0, 0, 0);
                c1 = __builtin_amdgcn_mfma_f32_16x16x32_bf16(A11, __builtin_bit_cast(bf16x8, rB1), c1, 0, 0, 0);
                int colw = (nt - half*26)*16 + m;
                #pragma unroll
                for (int r = 0; r < 4; r++) {
                    sP[(quad*4 + r)      * SP_STRIDE + colw] = f2bf(c0[r]);
                    sP[(16 + quad*4 + r) * SP_STRIDE + colw] = f2bf(c1[r]);
                }
                rB0 = nB0; rB1 = nB1; nt = ntn;
            }
        }
        __syncthreads();

        // ---- consume: atomic-free, exclusive sO writes ----
        if (half == 0) {
            if (wv == 0) {
                // o0e[v] = sum_{j<20} F[j] * P[j*16+v]
                float acc[16];
                #pragma unroll
                for (int v = 0; v < 16; v++) acc[v] = 0.f;
                #pragma unroll
                for (int jj = 0; jj < 10; jj++) {
                    int j = sub*10 + jj;
                    float f = Fv[j];
                    u16x8 p0 = *(const u16x8*)(Pr + j*16);
                    u16x8 p1 = *(const u16x8*)(Pr + j*16 + 8);
                    #pragma unroll
                    for (int v = 0; v < 8; v++) {
                        acc[v]   += f * bf2f(p0[v]);
                        acc[8+v] += f * bf2f(p1[v]);
                    }
                }
                #pragma unroll
                for (int v = 0; v < 16; v++) {
                    float tot = acc[v] + __shfl_down(acc[v], 32, 64);
                    if (sub == 0) sO[ce * SO_STRIDE + v] = tot;
                }
            } else if (wv == 1) {
                // o1o: cols 320 + j*4 + v
                float sA[4] = {0.f,0.f,0.f,0.f};
                float acc[3][4];
                #pragma unroll
                for (int i = 0; i < 3; i++)
                    #pragma unroll
                    for (int v = 0; v < 4; v++) acc[i][v] = 0.f;
                #pragma unroll
                for (int jj = 0; jj < 12; jj++) {
                    int j = sub*12 + jj;
                    u16x4 p = *(const u16x4*)(Pr + 320 + j*4);
                    float pv[4];
                    #pragma unroll
                    for (int v = 0; v < 4; v++) pv[v] = bf2f(p[v]);
                    if (j < 16) {
                        float f = Fv[20 + j];
                        #pragma unroll
                        for (int v = 0; v < 4; v++) sA[v] += f * pv[v];
                    } else {
                        int u = j - 16;
                        #pragma unroll
                        for (int i = 0; i < 3; i++) {
                            float f = Fv[36 + u*3 + i];
                            #pragma unroll
                            for (int v = 0; v < 4; v++) acc[i][v] += f * pv[v];
                        }
                    }
                }
                float s1v0 = sS1[ce][0], s1v1 = sS1[ce][1], s1v2 = sS1[ce][2];
                #pragma unroll
                for (int v = 0; v < 4; v++) {
                    float sAt = sA[v] + __shfl_down(sA[v], 32, 64);
                    float t0 = acc[0][v] + __shfl_down(acc[0][v], 32, 64);
                    float t1 = acc[1][v] + __shfl_down(acc[1][v], 32, 64);
                    float t2 = acc[2][v] + __shfl_down(acc[2][v], 32, 64);
                    if (sub == 0) {
                        sO[ce * SO_STRIDE + 16 + v*3 + 0] = sAt * s1v0 + t0;
                        sO[ce * SO_STRIDE + 16 + v*3 + 1] = sAt * s1v1 + t1;
                        sO[ce * SO_STRIDE + 16 + v*3 + 2] = sAt * s1v2 + t2;
                    }
                }
            }
        } else {
            if (wv == 2) {
                // o1e: cols j*4 + v
                float sD[4] = {0.f,0.f,0.f,0.f};
                float acc[3][4];
                #pragma unroll
                for (int i = 0; i < 3; i++)
                    #pragma unroll
                    for (int v = 0; v < 4; v++) acc[i][v] = 0.f;
                #pragma unroll
                for (int jj = 0; jj < 12; jj++) {
                    int j = sub*12 + jj;
                    u16x4 p = *(const u16x4*)(Pr + j*4);
                    float pv[4];
                    #pragma unroll
                    for (int v = 0; v < 4; v++) pv[v] = bf2f(p[v]);
                    if (j < 8) {
                        #pragma unroll
                        for (int i = 0; i < 3; i++) {
                            float f = Fv[60 + j*3 + i];
                            #pragma unroll
                            for (int v = 0; v < 4; v++) acc[i][v] += f * pv[v];
                        }
                    } else {
                        float f = Fv[84 + (j - 8)];
                        #pragma unroll
                        for (int v = 0; v < 4; v++) sD[v] += f * pv[v];
                    }
                }
                float s1v0 = sS1[ce][0], s1v1 = sS1[ce][1], s1v2 = sS1[ce][2];
                #pragma unroll
                for (int v = 0; v < 4; v++) {
                    float sDt = sD[v] + __shfl_down(sD[v], 32, 64);
                    float t0 = acc[0][v] + __shfl_down(acc[0][v], 32, 64);
                    float t1 = acc[1][v] + __shfl_down(acc[1][v], 32, 64);
                    float t2 = acc[2][v] + __shfl_down(acc[2][v], 32, 64);
                    if (sub == 0) {
                        sO[ce * SO_STRIDE + 28 + v*3 + 0] = sDt * s1v0 + t0;
                        sO[ce * SO_STRIDE + 28 + v*3 + 1] = sDt * s1v1 + t1;
                        sO[ce * SO_STRIDE + 28 + v*3 + 2] = sDt * s1v2 + t2;
                    }
                }
            } else if (wv == 3) {
                // o0o[v] = sum_{j<20} F[100+j] * P[96 + j*16 + v]
                float acc[16];
                #pragma unroll
                for (int v = 0; v < 16; v++) acc[v] = 0.f;
                #pragma unroll
                for (int jj = 0; jj < 10; jj++) {
                    int j = sub*10 + jj;
                    float f = Fv[100 + j];
                    u16x8 p0 = *(const u16x8*)(Pr + 96 + j*16);
                    u16x8 p1 = *(const u16x8*)(Pr + 96 + j*16 + 8);
                    #pragma unroll
                    for (int v = 0; v < 8; v++) {
                        acc[v]   += f * bf2f(p0[v]);
                        acc[8+v] += f * bf2f(p1[v]);
                    }
                }
                #pragma unroll
                for (int v = 0; v < 16; v++) {
                    float tot = acc[v] + __shfl_down(acc[v], 32, 64);
                    if (sub == 0) sO[ce * SO_STRIDE + 40 + v] = tot;
                }
            }
        }
        __syncthreads();
    }

    // ---- channel-major coalesced scatter (line-merged atomics, R1 pattern) ----
    for (int idx = tid; idx < TE * IRR; idx += NT) {
        int e = idx / IRR, c = idx - e * IRR;
        unsafeAtomicAdd(&accum[(size_t)sSrc[e] * IRR + c], sO[e * SO_STRIDE + c]);
    }
    if (tid < TE) unsafeAtomicAdd(&counts[sSrc[tid]], 1.0f);
}

__global__ void tp_divide(const float* __restrict__ accum,
                          const float* __restrict__ counts,
                          float* __restrict__ out)
{
    int idx = blockIdx.x * blockDim.x + threadIdx.x;
    if (idx < NNODE * IRR) {
        out[idx] = accum[idx] / fmaxf(counts[idx / IRR], 1.0f);
    }
}

extern "C" void kernel_launch(void* const* d_in, const int* in_sizes, int n_in,
                              void* d_out, int out_size, void* d_ws, size_t ws_size,
                              hipStream_t stream) {
    const float* node_attr  = (const float*)d_in[0];
    const float* edge_attr  = (const float*)d_in[1];
    const float* edge_sh    = (const float*)d_in[2];
    const float* fc_w1      = (const float*)d_in[3];
    const float* fc_b1      = (const float*)d_in[4];
    const float* fc_w2      = (const float*)d_in[5];
    const float* fc_b2      = (const float*)d_in[6];
    const int*   edge_index = (const int*)d_in[7];

    float* accum  = (float*)d_ws;
    float* counts = accum + (size_t)NNODE * IRR;
    unsigned short* W2T = (unsigned short*)(counts + NNODE);
    unsigned short* W1T = W2T + (size_t)WN * 64;

    hipMemsetAsync(d_ws, 0, ((size_t)NNODE * IRR + NNODE) * sizeof(float), stream);

    preconvert<<<(WN * 64 + 255) / 256, 256, 0, stream>>>(fc_w1, fc_b1, fc_w2, fc_b2, W1T, W2T);

    tp_fused<<<NBLK, NT, 0, stream>>>(node_attr, edge_attr, edge_sh, edge_index,
                                      W1T, W2T, accum, counts);

    tp_divide<<<(NNODE * IRR + NT - 1) / NT, NT, 0, stream>>>(accum, counts, (float*)d_out);
}

// Round 4
// 245.952 us; speedup vs baseline: 11.2098x; 1.0149x over previous
//
#include <hip/hip_runtime.h>

#define IRR    56
#define EF     48
#define WN     832
#define NEDGE  160000
#define NNODE  8000
#define TE     16          // edges per wave (= per block)
#define NT     64          // one wave per block, zero bariers of consequence
#define NBLK   (NEDGE / TE)

#define SG_STRIDE 60       // floats: 240B rows, 16B-aligned, 2-way bank alias (free)
#define SH_STRIDE 72       // ushorts: 144B rows, 16B-aligned
#define SF_STRIDE 121      // floats: odd stride -> 16 distinct banks for per-m reads

#define INV_SQRT3 0.5773502691896258f
#define INV_SQRT2 0.7071067811865476f
#define A_SCAL    0.22360679774997896f   // 1/sqrt(20)
#define A_VEC     0.20412414523193154f   // 1/sqrt(24)

typedef __bf16 bf16x8 __attribute__((ext_vector_type(8)));
typedef float  f32x4  __attribute__((ext_vector_type(4)));
typedef unsigned short u16x8 __attribute__((ext_vector_type(8)));
typedef unsigned short u16x4 __attribute__((ext_vector_type(4)));

__device__ __forceinline__ unsigned short f2bf(float f) {
    unsigned int u = __builtin_bit_cast(unsigned int, f);
    u += 0x7FFFu + ((u >> 16) & 1u);          // RNE
    return (unsigned short)(u >> 16);
}

// Zero accum/counts + build bf16 transposed weight tables [n][64] (coalesced reads).
__global__ void preconvert(const float* __restrict__ w1, const float* __restrict__ b1,
                           const float* __restrict__ w2, const float* __restrict__ b2,
                           unsigned short* __restrict__ W1T, unsigned short* __restrict__ W2T,
                           float* __restrict__ accum_counts)
{
    int i = blockIdx.x * 256 + threadIdx.x;
    if (i < NNODE * IRR + NNODE) accum_counts[i] = 0.f;
    if (i < EF * WN) { int k = i / WN, n = i - k * WN; W2T[n * 64 + k] = f2bf(w2[i]); }
    if (i < WN * 16) { int n = i >> 4, kk = EF + (i & 15); W2T[n * 64 + kk] = (kk == EF) ? f2bf(b2[n]) : (unsigned short)0; }
    if (i < EF * EF) { int k = i / EF, n = i - k * EF; W1T[n * 64 + k] = f2bf(w1[i]); }
    if (i < EF * 16) { int n = i >> 4, kk = EF + (i & 15); W1T[n * 64 + kk] = (kk == EF) ? f2bf(b1[n]) : (unsigned short)0; }
}

__global__ __launch_bounds__(NT) void tp_fused(
    const float* __restrict__ node_attr,
    const float* __restrict__ edge_attr,
    const float* __restrict__ edge_sh,
    const int*   __restrict__ edge_index,
    const unsigned short* __restrict__ W1T,
    const unsigned short* __restrict__ W2T,
    float* __restrict__ accum,
    float* __restrict__ counts)
{
    __shared__ __align__(16) float sGO[TE * SG_STRIDE];          // gather tile, later sO
    __shared__ __align__(16) unsigned short sH[TE * SH_STRIDE];  // H^T staging (A->B layout fix)
    __shared__ float sF[TE * SF_STRIDE];                         // TP features
    __shared__ float sS1[TE][4];
    __shared__ int   sSrc[TE], sDst[TE];

    const int lane = threadIdx.x;
    const int m    = lane & 15;    // edge owned by lane (and MFMA n/col index)
    const int quad = lane >> 4;
    const int e0   = blockIdx.x * TE;

    if (lane < TE)            sSrc[lane]      = edge_index[e0 + lane];
    else if (lane < 2 * TE)   sDst[lane - TE] = edge_index[NEDGE + e0 + lane - TE];
    __syncthreads();

    // ---- gather node rows (float4, 14 chunks/edge split across quads) ----
    {
        const float* nrow = node_attr + (size_t)sDst[m] * IRR;
        float* g = sGO + m * SG_STRIDE;
        #pragma unroll
        for (int t = 0; t < 3; t++) {
            int c = quad + t * 4;
            *(float4*)(g + c * 4) = *(const float4*)(nrow + c * 4);
        }
        if (quad < 2) { int c = 12 + quad; *(float4*)(g + c * 4) = *(const float4*)(nrow + c * 4); }
    }

    // ---- GEMM1, transposed: D = W1T_tile x edge_attr^T -> lane holds H[e=m][hid] ----
    {
        const float* arow = edge_attr + (size_t)(e0 + m) * EF;
        float av0[8], av1[8];
        {
            float4 p0 = *(const float4*)(arow + quad * 8);
            float4 p1 = *(const float4*)(arow + quad * 8 + 4);
            av0[0]=p0.x; av0[1]=p0.y; av0[2]=p0.z; av0[3]=p0.w;
            av0[4]=p1.x; av0[5]=p1.y; av0[6]=p1.z; av0[7]=p1.w;
        }
        if (quad < 2) {
            float4 p0 = *(const float4*)(arow + 32 + quad * 8);
            float4 p1 = *(const float4*)(arow + 32 + quad * 8 + 4);
            av1[0]=p0.x; av1[1]=p0.y; av1[2]=p0.z; av1[3]=p0.w;
            av1[4]=p1.x; av1[5]=p1.y; av1[6]=p1.z; av1[7]=p1.w;
        } else {
            #pragma unroll
            for (int j = 0; j < 8; j++) av1[j] = 0.f;
            if (quad == 2) av1[0] = 1.f;           // bias row k=48
        }
        u16x8 ub0, ub1;
        #pragma unroll
        for (int j = 0; j < 8; j++) { ub0[j] = f2bf(av0[j]); ub1[j] = f2bf(av1[j]); }
        bf16x8 hb0 = __builtin_bit_cast(bf16x8, ub0);
        bf16x8 hb1 = __builtin_bit_cast(bf16x8, ub1);

        #pragma unroll
        for (int nth = 0; nth < 3; nth++) {
            bf16x8 a0 = __builtin_bit_cast(bf16x8, *(const u16x8*)&W1T[(nth*16 + m)*64 + quad*8]);
            bf16x8 a1 = __builtin_bit_cast(bf16x8, *(const u16x8*)&W1T[(nth*16 + m)*64 + 32 + quad*8]);
            f32x4 c = {0.f, 0.f, 0.f, 0.f};
            c = __builtin_amdgcn_mfma_f32_16x16x32_bf16(a0, hb0, c, 0, 0, 0);
            c = __builtin_amdgcn_mfma_f32_16x16x32_bf16(a1, hb1, c, 0, 0, 0);
            // D[hid = nth*16+quad*4+r][e = m] -> sH[m][hid], relu'd
            u16x4 hp;
            #pragma unroll
            for (int r = 0; r < 4; r++) hp[r] = f2bf(fmaxf(c[r], 0.f));
            *(u16x4*)&sH[m * SH_STRIDE + nth*16 + quad*4] = hp;
        }
        if (quad == 3) {   // hid 48..63: bias-one column + zero pad
            u16x4 b = {0x3F80, 0, 0, 0}, z = {0, 0, 0, 0};
            *(u16x4*)&sH[m * SH_STRIDE + 48] = b;
            *(u16x4*)&sH[m * SH_STRIDE + 52] = z;
            *(u16x4*)&sH[m * SH_STRIDE + 56] = z;
            *(u16x4*)&sH[m * SH_STRIDE + 60] = z;
        }
    }
    __syncthreads();

    // ---- F features (quad0 lanes: full feature set for edge m) ----
    if (quad == 0) {
        const float* x = sGO + m * SG_STRIDE;
        float4 sh4 = *(const float4*)&edge_sh[(size_t)(e0 + m) * 4];
        const float s0 = sh4.x, sx = sh4.y, sy = sh4.z, sz = sh4.w;
        float* F = sF + m * SF_STRIDE;
        const float c0S = s0 * A_SCAL;
        const float c0V = s0 * A_VEC;
        const float cD3 = INV_SQRT3 * A_SCAL;
        const float cC2 = INV_SQRT2 * A_VEC;
        #pragma unroll
        for (int u = 0; u < 16; u++) {
            float x0e = x[u], x0o = x[40 + u];
            F[u]       = x0e * c0S;
            F[20 + u]  = x0e * A_VEC;
            F[84 + u]  = x0o * A_VEC;
            F[104 + u] = x0o * c0S;
        }
        #pragma unroll
        for (int u = 0; u < 4; u++) {
            float a0 = x[16 + u*3], a1 = x[16 + u*3 + 1], a2 = x[16 + u*3 + 2]; // x1o
            float b0 = x[28 + u*3], b1 = x[28 + u*3 + 1], b2 = x[28 + u*3 + 2]; // x1e
            F[16 + u]  = (a0*sx + a1*sy + a2*sz) * cD3;
            F[100 + u] = (b0*sx + b1*sy + b2*sz) * cD3;
            F[48 + u*3 + 0] = (b1*sz - b2*sy) * cC2;
            F[48 + u*3 + 1] = (b2*sx - b0*sz) * cC2;
            F[48 + u*3 + 2] = (b0*sy - b1*sx) * cC2;
            F[60 + u*3 + 0] = (a1*sz - a2*sy) * cC2;
            F[60 + u*3 + 1] = (a2*sx - a0*sz) * cC2;
            F[60 + u*3 + 2] = (a0*sy - a1*sx) * cC2;
            F[36 + u*3 + 0] = a0 * c0V;  F[36 + u*3 + 1] = a1 * c0V;  F[36 + u*3 + 2] = a2 * c0V;
            F[72 + u*3 + 0] = b0 * c0V;  F[72 + u*3 + 1] = b1 * c0V;  F[72 + u*3 + 2] = b2 * c0V;
        }
        sS1[m][0] = sx; sS1[m][1] = sy; sS1[m][2] = sz;
    }
    __syncthreads();

    // ---- H B-operand fragments: lane holds H[e=m][k=quad*8+j] ----
    bf16x8 HB0 = __builtin_bit_cast(bf16x8, *(const u16x8*)&sH[m * SH_STRIDE + quad*8]);
    bf16x8 HB1 = __builtin_bit_cast(bf16x8, *(const u16x8*)&sH[m * SH_STRIDE + 32 + quad*8]);

    // ---- fused GEMM2 + consume: P[e=m][n=nt*16+quad*4+r] stays in registers ----
    float oe[4]  = {0.f,0.f,0.f,0.f};
    float oo[4]  = {0.f,0.f,0.f,0.f};
    float sA[4]  = {0.f,0.f,0.f,0.f};
    float sD[4]  = {0.f,0.f,0.f,0.f};
    float t1o[12] = {0.f,0.f,0.f,0.f,0.f,0.f,0.f,0.f,0.f,0.f,0.f,0.f};
    float t1e[12] = {0.f,0.f,0.f,0.f,0.f,0.f,0.f,0.f,0.f,0.f,0.f,0.f};

    const float* Fm = sF + m * SF_STRIDE;
    u16x8 rW0 = *(const u16x8*)&W2T[(size_t)(m)*64 + quad*8];
    u16x8 rW1 = *(const u16x8*)&W2T[(size_t)(m)*64 + 32 + quad*8];

    for (int nt = 0; nt < 52; nt++) {
        int ntn = (nt < 51) ? nt + 1 : 51;
        u16x8 nW0 = *(const u16x8*)&W2T[(size_t)(ntn*16 + m)*64 + quad*8];
        u16x8 nW1 = *(const u16x8*)&W2T[(size_t)(ntn*16 + m)*64 + 32 + quad*8];
        f32x4 c = {0.f, 0.f, 0.f, 0.f};
        c = __builtin_amdgcn_mfma_f32_16x16x32_bf16(__builtin_bit_cast(bf16x8, rW0), HB0, c, 0, 0, 0);
        c = __builtin_amdgcn_mfma_f32_16x16x32_bf16(__builtin_bit_cast(bf16x8, rW1), HB1, c, 0, 0, 0);

        if (nt < 20) {                     // wA0 (nt<16) + wB0: o0e, channel quad*4+r
            float f = Fm[nt];
            #pragma unroll
            for (int r = 0; r < 4; r++) oe[r] += f * c[r];
        } else if (nt < 24) {              // wA1 dot path: j = (nt-20)*4+quad
            float f = Fm[20 + (nt - 20)*4 + quad];
            #pragma unroll
            for (int r = 0; r < 4; r++) sA[r] += f * c[r];
        } else if (nt < 26) {              // wB1+wC1 unified: u = (nt-24)*4+quad in 0..7
            int u = (nt - 24)*4 + quad;
            #pragma unroll
            for (int i = 0; i < 3; i++) {
                float f = Fm[36 + u*3 + i];
                #pragma unroll
                for (int r = 0; r < 4; r++) t1o[i*4 + r] += f * c[r];
            }
        } else if (nt < 28) {              // wB1e+wC1e unified: j = (nt-26)*4+quad in 0..7
            int j = (nt - 26)*4 + quad;
            #pragma unroll
            for (int i = 0; i < 3; i++) {
                float f = Fm[60 + j*3 + i];
                #pragma unroll
                for (int r = 0; r < 4; r++) t1e[i*4 + r] += f * c[r];
            }
        } else if (nt < 32) {              // wD1e dot path: u = (nt-28)*4+quad
            float f = Fm[84 + (nt - 28)*4 + quad];
            #pragma unroll
            for (int r = 0; r < 4; r++) sD[r] += f * c[r];
        } else {                           // wC0o (nt<36) + wD0o: o0o, channel 40+quad*4+r
            float f = Fm[68 + nt];
            #pragma unroll
            for (int r = 0; r < 4; r++) oo[r] += f * c[r];
        }
        rW0 = nW0; rW1 = nW1;
    }

    // ---- cross-quad butterfly reduction (o1o/o1e paths only) ----
    #pragma unroll
    for (int r = 0; r < 4; r++) {
        sA[r] += __shfl_xor(sA[r], 16, 64);  sA[r] += __shfl_xor(sA[r], 32, 64);
        sD[r] += __shfl_xor(sD[r], 16, 64);  sD[r] += __shfl_xor(sD[r], 32, 64);
    }
    #pragma unroll
    for (int i = 0; i < 12; i++) {
        t1o[i] += __shfl_xor(t1o[i], 16, 64);  t1o[i] += __shfl_xor(t1o[i], 32, 64);
        t1e[i] += __shfl_xor(t1e[i], 16, 64);  t1e[i] += __shfl_xor(t1e[i], 32, 64);
    }

    // ---- write per-edge outputs to sO (overlays dead sG) ----
    float* sO = sGO;
    {
        float4 v0; v0.x = oe[0]; v0.y = oe[1]; v0.z = oe[2]; v0.w = oe[3];
        float4 v1; v1.x = oo[0]; v1.y = oo[1]; v1.z = oo[2]; v1.w = oo[3];
        *(float4*)&sO[m * SG_STRIDE + quad*4]      = v0;   // channels 0..15
        *(float4*)&sO[m * SG_STRIDE + 40 + quad*4] = v1;   // channels 40..55
    }
    if (quad == 0) {
        float s1x = sS1[m][0], s1y = sS1[m][1], s1z = sS1[m][2];
        #pragma unroll
        for (int r = 0; r < 4; r++) {
            sO[m * SG_STRIDE + 16 + r*3 + 0] = sA[r] * s1x + t1o[0*4 + r];
            sO[m * SG_STRIDE + 16 + r*3 + 1] = sA[r] * s1y + t1o[1*4 + r];
            sO[m * SG_STRIDE + 16 + r*3 + 2] = sA[r] * s1z + t1o[2*4 + r];
        }
    } else if (quad == 1) {
        float s1x = sS1[m][0], s1y = sS1[m][1], s1z = sS1[m][2];
        #pragma unroll
        for (int r = 0; r < 4; r++) {
            sO[m * SG_STRIDE + 28 + r*3 + 0] = sD[r] * s1x + t1e[0*4 + r];
            sO[m * SG_STRIDE + 28 + r*3 + 1] = sD[r] * s1y + t1e[1*4 + r];
            sO[m * SG_STRIDE + 28 + r*3 + 2] = sD[r] * s1z + t1e[2*4 + r];
        }
    }
    __syncthreads();

    // ---- channel-major coalesced scatter (line-merged atomics) ----
    #pragma unroll
    for (int it = 0; it < 14; it++) {
        int idx = it * 64 + lane;          // < 896 = 16*56
        int e = idx / IRR, ch = idx - e * IRR;
        unsafeAtomicAdd(&accum[(size_t)sSrc[e] * IRR + ch], sO[e * SG_STRIDE + ch]);
    }
    if (lane < TE) unsafeAtomicAdd(&counts[sSrc[lane]], 1.0f);
}

__global__ void tp_divide(const float* __restrict__ accum,
                          const float* __restrict__ counts,
                          float* __restrict__ out)
{
    int idx = blockIdx.x * blockDim.x + threadIdx.x;
    if (idx < NNODE * IRR) {
        out[idx] = accum[idx] / fmaxf(counts[idx / IRR], 1.0f);
    }
}

extern "C" void kernel_launch(void* const* d_in, const int* in_sizes, int n_in,
                              void* d_out, int out_size, void* d_ws, size_t ws_size,
                              hipStream_t stream) {
    const float* node_attr  = (const float*)d_in[0];
    const float* edge_attr  = (const float*)d_in[1];
    const float* edge_sh    = (const float*)d_in[2];
    const float* fc_w1      = (const float*)d_in[3];
    const float* fc_b1      = (const float*)d_in[4];
    const float* fc_w2      = (const float*)d_in[5];
    const float* fc_b2      = (const float*)d_in[6];
    const int*   edge_index = (const int*)d_in[7];

    float* accum  = (float*)d_ws;
    float* counts = accum + (size_t)NNODE * IRR;
    unsigned short* W2T = (unsigned short*)(counts + NNODE);
    unsigned short* W1T = W2T + (size_t)WN * 64;

    preconvert<<<(NNODE * IRR + NNODE + 255) / 256, 256, 0, stream>>>(
        fc_w1, fc_b1, fc_w2, fc_b2, W1T, W2T, accum);

    tp_fused<<<NBLK, NT, 0, stream>>>(node_attr, edge_attr, edge_sh, edge_index,
                                      W1T, W2T, accum, counts);

    tp_divide<<<(NNODE * IRR + 255) / 256, 256, 0, stream>>>(accum, counts, (float*)d_out);
}